// Round 1
// baseline (3183.345 us; speedup 1.0000x reference)
//
#include <hip/hip_runtime.h>
#include <cstdint>

typedef __bf16 bf16;
typedef __bf16 bf16x4 __attribute__((ext_vector_type(4)));
typedef __bf16 bf16x8 __attribute__((ext_vector_type(8)));
typedef float  f32x4  __attribute__((ext_vector_type(4)));

// async global->LDS, 16B per lane. LDS dest must be wave-uniform base + lane*16.
__device__ __forceinline__ void gld_lds16(const bf16* g, bf16* l) {
  __builtin_amdgcn_global_load_lds(
      (__attribute__((address_space(1))) void*)(g),
      (__attribute__((address_space(3))) void*)(l),
      16, 0, 0);
}

__device__ __forceinline__ float gelu_f(float x) {
  float u = 0.7978845608028654f * (x + 0.044715f * x * x * x);
  float t = 1.0f - 2.0f / (__expf(2.0f * u) + 1.0f);   // tanh(u)
  return 0.5f * x * (1.0f + t);
}

// ---------------------------------------------------------------- im2col ----
// x (4,4,128,128,128) fp32 -> patches bf16 [2048][16384], col = c*4096+i*256+j*16+kk
__global__ void im2col_k(const float* __restrict__ x, bf16* __restrict__ patches) {
  int col4 = blockIdx.x * 256 + threadIdx.x;   // 0..4095 (4 elems each)
  int m    = blockIdx.y;                       // 0..2047 token row
  int col  = col4 * 4;
  int kk = col & 15, j = (col >> 4) & 15, i = (col >> 8) & 15, c = col >> 12;
  int b = m >> 9, t = m & 511;
  int d = t >> 6, hh = (t >> 3) & 7, ww = t & 7;
  long src = ((((long)(b * 4 + c) * 128 + (d * 16 + i)) * 128 + (hh * 16 + j)) * 128)
             + (ww * 16 + kk);
  float4 v = *(const float4*)(x + src);
  bf16x4 o; o[0] = (bf16)v.x; o[1] = (bf16)v.y; o[2] = (bf16)v.z; o[3] = (bf16)v.w;
  *(bf16x4*)(patches + (long)m * 16384 + col) = o;
}

// ------------------------------------------------------ fp32 -> bf16 copy ----
__global__ void cvt_k(const float* __restrict__ src, bf16* __restrict__ dst) {
  long i = (long)blockIdx.x * 256 + threadIdx.x;
  float4 v = *(const float4*)(src + i * 4);
  bf16x4 o; o[0] = (bf16)v.x; o[1] = (bf16)v.y; o[2] = (bf16)v.z; o[3] = (bf16)v.w;
  *(bf16x4*)(dst + i * 4) = o;
}

// ------------------------------------------- QKV weight transpose+convert ----
// src Wq (L,H,768,64) fp32 -> dst[l][qoff + h*64 + e][d] bf16 (row len 768)
__global__ void tp_qkv(const float* __restrict__ src, bf16* __restrict__ dst, int qoff) {
  __shared__ float tile[64][65];
  int z = blockIdx.y, dt = blockIdx.x;         // z = l*12+h, dt = d-tile (0..11)
  int l = z / 12, hh = z % 12;
  const float* s = src + (long)z * 49152;      // 768*64
  int tx = threadIdx.x, ty = threadIdx.y;
#pragma unroll
  for (int q = 0; q < 16; q++) {
    int dl = q * 4 + ty;
    tile[dl][tx] = s[(long)(dt * 64 + dl) * 64 + tx];
  }
  __syncthreads();
#pragma unroll
  for (int q = 0; q < 16; q++) {
    int el = q * 4 + ty;
    dst[((long)l * 2304 + qoff + hh * 64 + el) * 768 + dt * 64 + tx] = (bf16)tile[tx][el];
  }
}

// -------------------------------------------- generic transpose + convert ----
// src (Z,R,C) fp32 -> dst (Z,C,R) bf16
__global__ void tp_gen(const float* __restrict__ src, bf16* __restrict__ dst, int R, int C) {
  __shared__ float tile[64][65];
  int z = blockIdx.z, rt = blockIdx.x, ct = blockIdx.y;
  const float* s = src + (long)z * R * C;
  bf16* d = dst + (long)z * R * C;
  int tx = threadIdx.x, ty = threadIdx.y;
#pragma unroll
  for (int q = 0; q < 16; q++) {
    int rl = q * 4 + ty;
    tile[rl][tx] = s[(long)(rt * 64 + rl) * C + ct * 64 + tx];
  }
  __syncthreads();
#pragma unroll
  for (int q = 0; q < 16; q++) {
    int cl = q * 4 + ty;
    d[(long)(ct * 64 + cl) * R + rt * 64 + tx] = (bf16)tile[tx][cl];
  }
}

// ------------------------------------------------------------- layernorm ----
// h (2048,768) fp32 -> y bf16 = (h-mu)*rsqrt(var+eps)*g + b
__global__ __launch_bounds__(256) void ln_k(const float* __restrict__ h,
                                            const float* __restrict__ g,
                                            const float* __restrict__ b,
                                            bf16* __restrict__ y) {
  int row = blockIdx.x, tid = threadIdx.x;
  const float* hr = h + (long)row * 768;
  float v0 = hr[tid], v1 = hr[tid + 256], v2 = hr[tid + 512];
  float s = v0 + v1 + v2, s2 = v0 * v0 + v1 * v1 + v2 * v2;
#pragma unroll
  for (int o = 32; o; o >>= 1) { s += __shfl_down(s, o); s2 += __shfl_down(s2, o); }
  __shared__ float sm[4], sm2[4], mu_s, rs_s;
  int lane = tid & 63, wv = tid >> 6;
  if (!lane) { sm[wv] = s; sm2[wv] = s2; }
  __syncthreads();
  if (tid == 0) {
    float ts = sm[0] + sm[1] + sm[2] + sm[3];
    float ts2 = sm2[0] + sm2[1] + sm2[2] + sm2[3];
    float mu = ts * (1.f / 768.f);
    float var = ts2 * (1.f / 768.f) - mu * mu;
    mu_s = mu; rs_s = rsqrtf(var + 1e-5f);
  }
  __syncthreads();
  float mu = mu_s, rs = rs_s;
  bf16* yr = y + (long)row * 768;
  yr[tid]       = (bf16)((v0 - mu) * rs * g[tid]       + b[tid]);
  yr[tid + 256] = (bf16)((v1 - mu) * rs * g[tid + 256] + b[tid + 256]);
  yr[tid + 512] = (bf16)((v2 - mu) * rs * g[tid + 512] + b[tid + 512]);
}

// --------------------------------------------------------------- softmax ----
// S (48*512,512) fp32 -> P bf16, row softmax. One wave per row.
__global__ __launch_bounds__(256) void softmax_k(const float* __restrict__ S,
                                                 bf16* __restrict__ P) {
  int row = blockIdx.x * 4 + (threadIdx.x >> 6);
  int lane = threadIdx.x & 63;
  const float* sr = S + (long)row * 512 + lane * 8;
  float4 a = *(const float4*)sr, b = *(const float4*)(sr + 4);
  float v[8] = {a.x, a.y, a.z, a.w, b.x, b.y, b.z, b.w};
  float mx = v[0];
#pragma unroll
  for (int i = 1; i < 8; i++) mx = fmaxf(mx, v[i]);
#pragma unroll
  for (int o = 1; o < 64; o <<= 1) mx = fmaxf(mx, __shfl_xor(mx, o));
  float sum = 0.f;
#pragma unroll
  for (int i = 0; i < 8; i++) { v[i] = __expf(v[i] - mx); sum += v[i]; }
#pragma unroll
  for (int o = 1; o < 64; o <<= 1) sum += __shfl_xor(sum, o);
  float inv = 1.0f / sum;
  bf16x8 o8;
#pragma unroll
  for (int i = 0; i < 8; i++) o8[i] = (bf16)(v[i] * inv);
  *(bf16x8*)(P + (long)row * 512 + lane * 8) = o8;
}

// -------------------------------------------------------------- GEMM B^T ----
// C[m][n] = sum_k A[m][k]*B[n][k]. A (M,K) bf16, B (N,K) bf16, acc fp32.
// Per-wave 64x64 via 4x4 grid of 16x16x32 MFMAs. Wave grid (BM/64)x(BN/64).
// MODE: 0 patch(+bp+pos->h)  1 qkv(->Q,K,Vt +bias)  2 scores(*0.125->S f32)
//       3 pv(h+=)  4 mlp1(gelu(+b)->U bf16)  5 mlp2(h+=acc+b)
template <int BM, int BN, int MODE>
__global__ __launch_bounds__((BM / 64) * (BN / 64) * 64)
void gemm_bt(const bf16* __restrict__ Ab, const bf16* __restrict__ Bb,
             int M, int N, int K, long sAz, long sBz,
             const float* __restrict__ b0, const float* __restrict__ b1,
             const float* __restrict__ b2, const float* __restrict__ pos,
             float* __restrict__ HO, bf16* __restrict__ O1,
             bf16* __restrict__ O2, bf16* __restrict__ O3) {
  constexpr int WM = BM / 64, WN = BN / 64, NT = WM * WN * 64;
  __shared__ bf16 As[BM * 32];
  __shared__ bf16 Bs[BN * 32];
  const int tid = threadIdx.x;
  const int z = blockIdx.z;
  const bf16* A = Ab + (long)z * sAz;
  const bf16* B = Bb + (long)z * sBz;
  const int m0 = blockIdx.x * BM, n0 = blockIdx.y * BN;
  const int lane = tid & 63, wave = tid >> 6;
  const int wm = wave / WN, wn = wave % WN;
  const int mrow = lane & 15, quad = lane >> 4;
  f32x4 acc[4][4];
#pragma unroll
  for (int i = 0; i < 4; i++)
#pragma unroll
    for (int j = 0; j < 4; j++) acc[i][j] = f32x4{0.f, 0.f, 0.f, 0.f};

  for (int k0 = 0; k0 < K; k0 += 32) {
#pragma unroll
    for (int i = 0; i < (BM * 4) / NT; ++i) {
      int ci = tid + i * NT;                               // 16B chunk id
      gld_lds16(A + (long)(m0 + (ci >> 2)) * K + k0 + (ci & 3) * 8, As + ci * 8);
    }
#pragma unroll
    for (int i = 0; i < (BN * 4) / NT; ++i) {
      int ci = tid + i * NT;
      gld_lds16(B + (long)(n0 + (ci >> 2)) * K + k0 + (ci & 3) * 8, Bs + ci * 8);
    }
    __syncthreads();
    bf16x8 af[4], bfv[4];
#pragma unroll
    for (int i = 0; i < 4; i++)
      af[i] = *(const bf16x8*)(As + (wm * 64 + i * 16 + mrow) * 32 + quad * 8);
#pragma unroll
    for (int j = 0; j < 4; j++)
      bfv[j] = *(const bf16x8*)(Bs + (wn * 64 + j * 16 + mrow) * 32 + quad * 8);
#pragma unroll
    for (int i = 0; i < 4; i++)
#pragma unroll
      for (int j = 0; j < 4; j++)
        acc[i][j] = __builtin_amdgcn_mfma_f32_16x16x32_bf16(af[i], bfv[j], acc[i][j], 0, 0, 0);
    __syncthreads();
  }

#pragma unroll
  for (int i = 0; i < 4; i++) {
#pragma unroll
    for (int j = 0; j < 4; j++) {
#pragma unroll
      for (int r = 0; r < 4; r++) {
        int gm = m0 + wm * 64 + i * 16 + quad * 4 + r;     // C/D: row=quad*4+reg
        int gn = n0 + wn * 64 + j * 16 + mrow;             //      col=lane&15
        float v = acc[i][j][r];
        if constexpr (MODE == 0) {
          HO[(long)gm * N + gn] = v + b0[gn] + pos[(gm & 511) * 768 + gn];
        } else if constexpr (MODE == 1) {
          int b_ = gm >> 9, tok = gm & 511;
          int seg = gn / 768, nn = gn - seg * 768;
          int head = nn >> 6, e = nn & 63;
          long bh = (long)(b_ * 12 + head);
          if (seg == 0)      O1[(bh * 512 + tok) * 64 + e] = (bf16)(v + b0[nn]);
          else if (seg == 1) O2[(bh * 512 + tok) * 64 + e] = (bf16)(v + b1[nn]);
          else               O3[(bh * 64 + e) * 512 + tok] = (bf16)(v + b2[nn]);
        } else if constexpr (MODE == 2) {
          HO[(long)z * 262144 + (long)gm * 512 + gn] = v * 0.125f;
        } else if constexpr (MODE == 3) {
          int b_ = z / 12, head = z % 12;
          HO[((long)(b_ * 512 + gm)) * 768 + head * 64 + gn] += v;
        } else if constexpr (MODE == 4) {
          O1[(long)gm * N + gn] = (bf16)gelu_f(v + b0[gn]);
        } else {
          HO[(long)gm * N + gn] += v + b0[gn];
        }
      }
    }
  }
}

// ---------------------------------------------------------------- launch ----
extern "C" void kernel_launch(void* const* d_in, const int* in_sizes, int n_in,
                              void* d_out, int out_size, void* d_ws, size_t ws_size,
                              hipStream_t stream) {
  const float* x     = (const float*)d_in[0];
  const float* Wp    = (const float*)d_in[1];
  const float* bp    = (const float*)d_in[2];
  const float* pos   = (const float*)d_in[3];
  const float* ln1_g = (const float*)d_in[4];
  const float* ln1_b = (const float*)d_in[5];
  const float* Wq    = (const float*)d_in[6];
  const float* bq    = (const float*)d_in[7];
  const float* Wk    = (const float*)d_in[8];
  const float* bk    = (const float*)d_in[9];
  const float* Wv    = (const float*)d_in[10];
  const float* bv    = (const float*)d_in[11];
  const float* ln2_g = (const float*)d_in[12];
  const float* ln2_b = (const float*)d_in[13];
  const float* W1    = (const float*)d_in[14];
  const float* b1    = (const float*)d_in[15];
  const float* W2    = (const float*)d_in[16];
  const float* b2    = (const float*)d_in[17];
  float* h = (float*)d_out;   // (4,512,768) residual stream lives in d_out

  char* wsp = (char*)d_ws;
  size_t off = 0;
  auto take = [&](size_t n) { char* p = wsp + off; off += (n + 255) & ~(size_t)255; return p; };
  bf16* patches = (bf16*)take((size_t)2048 * 16384 * 2);  // 64MB; reused as S (48MB)
  float* S      = (float*)patches;
  bf16* Wp_bt   = (bf16*)take((size_t)768 * 16384 * 2);
  bf16* Wqkv    = (bf16*)take((size_t)12 * 2304 * 768 * 2);
  bf16* W1t     = (bf16*)take((size_t)12 * 3072 * 768 * 2);
  bf16* W2t     = (bf16*)take((size_t)12 * 3072 * 768 * 2);
  bf16* Y       = (bf16*)take((size_t)2048 * 768 * 2);
  bf16* Qb      = (bf16*)take((size_t)48 * 512 * 64 * 2);
  bf16* Kb      = (bf16*)take((size_t)48 * 512 * 64 * 2);
  bf16* Vt      = (bf16*)take((size_t)48 * 512 * 64 * 2);
  bf16* Pb      = (bf16*)take((size_t)48 * 512 * 512 * 2);
  bf16* Ub      = (bf16*)take((size_t)2048 * 3072 * 2);

  // weight/activation prep
  im2col_k<<<dim3(16, 2048), 256, 0, stream>>>(x, patches);
  cvt_k<<<dim3(12288), 256, 0, stream>>>(Wp, Wp_bt);            // 768*16384/4/256
  tp_qkv<<<dim3(12, 144), dim3(64, 4), 0, stream>>>(Wq, Wqkv, 0);
  tp_qkv<<<dim3(12, 144), dim3(64, 4), 0, stream>>>(Wk, Wqkv, 768);
  tp_qkv<<<dim3(12, 144), dim3(64, 4), 0, stream>>>(Wv, Wqkv, 1536);
  tp_gen<<<dim3(12, 48, 12), dim3(64, 4), 0, stream>>>(W1, W1t, 768, 3072);
  tp_gen<<<dim3(48, 12, 12), dim3(64, 4), 0, stream>>>(W2, W2t, 3072, 768);

  // patch embed: h = patches @ Wp^T + bp + pos
  gemm_bt<64, 128, 0><<<dim3(32, 6), 128, 0, stream>>>(
      patches, Wp_bt, 2048, 768, 16384, 0, 0, bp, nullptr, nullptr, pos,
      h, nullptr, nullptr, nullptr);

  for (int l = 0; l < 12; l++) {
    ln_k<<<2048, 256, 0, stream>>>(h, ln1_g + l * 768, ln1_b + l * 768, Y);
    gemm_bt<64, 128, 1><<<dim3(32, 18), 128, 0, stream>>>(
        Y, Wqkv + (size_t)l * 2304 * 768, 2048, 2304, 768, 0, 0,
        bq + l * 768, bk + l * 768, bv + l * 768, nullptr,
        nullptr, Qb, Kb, Vt);
    gemm_bt<128, 128, 2><<<dim3(4, 4, 48), 256, 0, stream>>>(
        Qb, Kb, 512, 512, 64, 512 * 64, 512 * 64,
        nullptr, nullptr, nullptr, nullptr, S, nullptr, nullptr, nullptr);
    softmax_k<<<dim3(6144), 256, 0, stream>>>(S, Pb);
    gemm_bt<128, 64, 3><<<dim3(4, 1, 48), 128, 0, stream>>>(
        Pb, Vt, 512, 64, 512, 512 * 512, 64 * 512,
        nullptr, nullptr, nullptr, nullptr, h, nullptr, nullptr, nullptr);
    ln_k<<<2048, 256, 0, stream>>>(h, ln2_g + l * 768, ln2_b + l * 768, Y);
    gemm_bt<64, 128, 4><<<dim3(32, 24), 128, 0, stream>>>(
        Y, W1t + (size_t)l * 3072 * 768, 2048, 3072, 768, 0, 0,
        b1 + l * 3072, nullptr, nullptr, nullptr, nullptr, Ub, nullptr, nullptr);
    gemm_bt<64, 128, 5><<<dim3(32, 6), 128, 0, stream>>>(
        Ub, W2t + (size_t)l * 3072 * 768, 2048, 768, 3072, 0, 0,
        b2 + l * 768, nullptr, nullptr, nullptr, h, nullptr, nullptr, nullptr);
  }
}

// Round 3
// 2348.909 us; speedup vs baseline: 1.3552x; 1.3552x over previous
//
#include <hip/hip_runtime.h>
#include <cstdint>

typedef __bf16 bf16;
typedef __bf16 bf16x4 __attribute__((ext_vector_type(4)));
typedef __bf16 bf16x8 __attribute__((ext_vector_type(8)));
typedef float  f32x4  __attribute__((ext_vector_type(4)));

// async global->LDS, 16B per lane. LDS dest must be wave-uniform base + lane*16.
__device__ __forceinline__ void gld_lds16(const bf16* g, bf16* l) {
  __builtin_amdgcn_global_load_lds(
      (__attribute__((address_space(1))) void*)(g),
      (__attribute__((address_space(3))) void*)(l),
      16, 0, 0);
}

__device__ __forceinline__ float gelu_f(float x) {
  float u = 0.7978845608028654f * (x + 0.044715f * x * x * x);
  float t = 1.0f - 2.0f / (__expf(2.0f * u) + 1.0f);   // tanh(u)
  return 0.5f * x * (1.0f + t);
}

// ---------------------------------------------------------------- im2col ----
// x (4,4,128,128,128) fp32 -> patches bf16 [2048][16384], col = c*4096+i*256+j*16+kk
__global__ void im2col_k(const float* __restrict__ x, bf16* __restrict__ patches) {
  int col4 = blockIdx.x * 256 + threadIdx.x;   // 0..4095 (4 elems each)
  int m    = blockIdx.y;                       // 0..2047 token row
  int col  = col4 * 4;
  int kk = col & 15, j = (col >> 4) & 15, i = (col >> 8) & 15, c = col >> 12;
  int b = m >> 9, t = m & 511;
  int d = t >> 6, hh = (t >> 3) & 7, ww = t & 7;
  long src = ((((long)(b * 4 + c) * 128 + (d * 16 + i)) * 128 + (hh * 16 + j)) * 128)
             + (ww * 16 + kk);
  float4 v = *(const float4*)(x + src);
  bf16x4 o; o[0] = (bf16)v.x; o[1] = (bf16)v.y; o[2] = (bf16)v.z; o[3] = (bf16)v.w;
  *(bf16x4*)(patches + (long)m * 16384 + col) = o;
}

// ------------------------------------------------------ fp32 -> bf16 copy ----
__global__ void cvt_k(const float* __restrict__ src, bf16* __restrict__ dst) {
  long i = (long)blockIdx.x * 256 + threadIdx.x;
  float4 v = *(const float4*)(src + i * 4);
  bf16x4 o; o[0] = (bf16)v.x; o[1] = (bf16)v.y; o[2] = (bf16)v.z; o[3] = (bf16)v.w;
  *(bf16x4*)(dst + i * 4) = o;
}

// ------------------------------------------- QKV weight transpose+convert ----
// src Wq (L,H,768,64) fp32 -> dst[l][qoff + h*64 + e][d] bf16 (row len 768)
__global__ void tp_qkv(const float* __restrict__ src, bf16* __restrict__ dst, int qoff) {
  __shared__ float tile[64][65];
  int z = blockIdx.y, dt = blockIdx.x;         // z = l*12+h, dt = d-tile (0..11)
  int l = z / 12, hh = z % 12;
  const float* s = src + (long)z * 49152;      // 768*64
  int tx = threadIdx.x, ty = threadIdx.y;
#pragma unroll
  for (int q = 0; q < 16; q++) {
    int dl = q * 4 + ty;
    tile[dl][tx] = s[(long)(dt * 64 + dl) * 64 + tx];
  }
  __syncthreads();
#pragma unroll
  for (int q = 0; q < 16; q++) {
    int el = q * 4 + ty;
    dst[((long)l * 2304 + qoff + hh * 64 + el) * 768 + dt * 64 + tx] = (bf16)tile[tx][el];
  }
}

// -------------------------------------------- generic transpose + convert ----
// src (Z,R,C) fp32 -> dst (Z,C,R) bf16
__global__ void tp_gen(const float* __restrict__ src, bf16* __restrict__ dst, int R, int C) {
  __shared__ float tile[64][65];
  int z = blockIdx.z, rt = blockIdx.x, ct = blockIdx.y;
  const float* s = src + (long)z * R * C;
  bf16* d = dst + (long)z * R * C;
  int tx = threadIdx.x, ty = threadIdx.y;
#pragma unroll
  for (int q = 0; q < 16; q++) {
    int rl = q * 4 + ty;
    tile[rl][tx] = s[(long)(rt * 64 + rl) * C + ct * 64 + tx];
  }
  __syncthreads();
#pragma unroll
  for (int q = 0; q < 16; q++) {
    int cl = q * 4 + ty;
    d[(long)(ct * 64 + cl) * R + rt * 64 + tx] = (bf16)tile[tx][cl];
  }
}

// ---------------------------------------------- fused split-K reduce + LN ----
// h_new[row][c] = (h_in?:0) + sum_s P[s][row][c] + (eb?:0) + (pos?:0)
// write h_out; if g: LN(h_new)*g+b -> Y (bf16).
__global__ __launch_bounds__(256) void lnred_k(
    const float* __restrict__ h_in, const float* __restrict__ P, int ns,
    const float* __restrict__ eb, const float* __restrict__ pos,
    const float* __restrict__ g, const float* __restrict__ b,
    float* __restrict__ h_out, bf16* __restrict__ Y) {
  int row = blockIdx.x, tid = threadIdx.x;
  float v[3];
#pragma unroll
  for (int j = 0; j < 3; j++) {
    int c = tid + j * 256;
    float acc = h_in ? h_in[(long)row * 768 + c] : 0.f;
    if (eb)  acc += eb[c];
    if (pos) acc += pos[(row & 511) * 768 + c];
    if (P)
      for (int s = 0; s < ns; s++) acc += P[(long)s * 1572864 + (long)row * 768 + c];
    v[j] = acc;
    h_out[(long)row * 768 + c] = acc;
  }
  if (!g) return;
  float s1 = v[0] + v[1] + v[2];
  float s2 = v[0] * v[0] + v[1] * v[1] + v[2] * v[2];
#pragma unroll
  for (int o = 32; o; o >>= 1) { s1 += __shfl_down(s1, o); s2 += __shfl_down(s2, o); }
  __shared__ float sm[4], sm2[4], mu_s, rs_s;
  int lane = tid & 63, wv = tid >> 6;
  if (!lane) { sm[wv] = s1; sm2[wv] = s2; }
  __syncthreads();
  if (tid == 0) {
    float ts = sm[0] + sm[1] + sm[2] + sm[3];
    float ts2 = sm2[0] + sm2[1] + sm2[2] + sm2[3];
    float mu = ts * (1.f / 768.f);
    float var = ts2 * (1.f / 768.f) - mu * mu;
    mu_s = mu; rs_s = rsqrtf(var + 1e-5f);
  }
  __syncthreads();
  float mu = mu_s, rs = rs_s;
  bf16* yr = Y + (long)row * 768;
#pragma unroll
  for (int j = 0; j < 3; j++) {
    int c = tid + j * 256;
    yr[c] = (bf16)((v[j] - mu) * rs * g[c] + b[c]);
  }
}

// --------------------------------------------------------------- softmax ----
// S (48*512,512) bf16 -> P bf16, row softmax. One wave per row.
__global__ __launch_bounds__(256) void softmax_k(const bf16* __restrict__ S,
                                                 bf16* __restrict__ P) {
  int row = blockIdx.x * 4 + (threadIdx.x >> 6);
  int lane = threadIdx.x & 63;
  const bf16* sr = S + (long)row * 512 + lane * 8;
  bf16x8 a8 = *(const bf16x8*)sr;
  float v[8];
#pragma unroll
  for (int i = 0; i < 8; i++) v[i] = (float)a8[i];
  float mx = v[0];
#pragma unroll
  for (int i = 1; i < 8; i++) mx = fmaxf(mx, v[i]);
#pragma unroll
  for (int o = 1; o < 64; o <<= 1) mx = fmaxf(mx, __shfl_xor(mx, o));
  float sum = 0.f;
#pragma unroll
  for (int i = 0; i < 8; i++) { v[i] = __expf(v[i] - mx); sum += v[i]; }
#pragma unroll
  for (int o = 1; o < 64; o <<= 1) sum += __shfl_xor(sum, o);
  float inv = 1.0f / sum;
  bf16x8 o8;
#pragma unroll
  for (int i = 0; i < 8; i++) o8[i] = (bf16)(v[i] * inv);
  *(bf16x8*)(P + (long)row * 512 + lane * 8) = o8;
}

// -------------------------------------------------------------- GEMM B^T ----
// C[m][n] = sum_k A[m][k]*B[n][k]. A (M,Kstride) bf16, B (N,Kstride) bf16.
// Per-wave 64x64 via 4x4 grid of 16x16x32 MFMAs. Wave grid (BM/64)x(BN/64).
// MODE: 0 split-K partial (z=split, kStart=z*kChunk) -> PO[z][m][n] fp32
//       1 qkv (->Q,K,Vt +bias)
//       2 scores (z=bh, *0.125 -> bf16 O1[z][m][n], n=512)
//       3 pv split-K (z=bh*4+s) -> PO[s][b*512+m][head*64+n] fp32
//       4 mlp1 (gelu(v+b0) -> bf16 O1[m][n], n=3072)
template <int BM, int BN, int MODE>
__global__ __launch_bounds__((BM / 64) * (BN / 64) * 64)
void gemm_bt(const bf16* __restrict__ Ab, const bf16* __restrict__ Bb,
             int M, int N, int Kstride, int kChunk, int kLen, long sAz, long sBz,
             const float* __restrict__ b0, const float* __restrict__ b1,
             const float* __restrict__ b2,
             float* __restrict__ PO, bf16* __restrict__ O1,
             bf16* __restrict__ O2, bf16* __restrict__ O3) {
  constexpr int WM = BM / 64, WN = BN / 64, NT = WM * WN * 64;
  __shared__ bf16 As[BM * 32];
  __shared__ bf16 Bs[BN * 32];
  const int tid = threadIdx.x;
  const int z = blockIdx.z;
  int kStart = 0;
  long aOff = 0, bOff = 0;
  if constexpr (MODE == 0) kStart = z * kChunk;
  if constexpr (MODE == 2) { aOff = (long)z * sAz; bOff = (long)z * sBz; }
  if constexpr (MODE == 3) {
    int bh = z >> 2;
    aOff = (long)bh * sAz; bOff = (long)bh * sBz;
    kStart = (z & 3) * kChunk;
  }
  const bf16* A = Ab + aOff;
  const bf16* B = Bb + bOff;
  const int m0 = blockIdx.x * BM, n0 = blockIdx.y * BN;
  const int lane = tid & 63, wave = tid >> 6;
  const int wm = wave / WN, wn = wave % WN;
  const int mrow = lane & 15, quad = lane >> 4;
  f32x4 acc[4][4];
#pragma unroll
  for (int i = 0; i < 4; i++)
#pragma unroll
    for (int j = 0; j < 4; j++) acc[i][j] = f32x4{0.f, 0.f, 0.f, 0.f};

  for (int k0 = 0; k0 < kLen; k0 += 32) {
#pragma unroll
    for (int i = 0; i < (BM * 4) / NT; ++i) {
      int ci = tid + i * NT;                               // 16B chunk id
      gld_lds16(A + (long)(m0 + (ci >> 2)) * Kstride + kStart + k0 + (ci & 3) * 8,
                As + ci * 8);
    }
#pragma unroll
    for (int i = 0; i < (BN * 4) / NT; ++i) {
      int ci = tid + i * NT;
      gld_lds16(B + (long)(n0 + (ci >> 2)) * Kstride + kStart + k0 + (ci & 3) * 8,
                Bs + ci * 8);
    }
    __syncthreads();
    bf16x8 af[4], bfv[4];
#pragma unroll
    for (int i = 0; i < 4; i++)
      af[i] = *(const bf16x8*)(As + (wm * 64 + i * 16 + mrow) * 32 + quad * 8);
#pragma unroll
    for (int j = 0; j < 4; j++)
      bfv[j] = *(const bf16x8*)(Bs + (wn * 64 + j * 16 + mrow) * 32 + quad * 8);
#pragma unroll
    for (int i = 0; i < 4; i++)
#pragma unroll
      for (int j = 0; j < 4; j++)
        acc[i][j] = __builtin_amdgcn_mfma_f32_16x16x32_bf16(af[i], bfv[j], acc[i][j], 0, 0, 0);
    __syncthreads();
  }

  int s3 = 0, b3 = 0, h3 = 0;
  if constexpr (MODE == 3) { s3 = z & 3; int bh = z >> 2; b3 = bh / 12; h3 = bh % 12; }
#pragma unroll
  for (int i = 0; i < 4; i++) {
#pragma unroll
    for (int j = 0; j < 4; j++) {
#pragma unroll
      for (int r = 0; r < 4; r++) {
        int gm = m0 + wm * 64 + i * 16 + quad * 4 + r;     // C/D: row=quad*4+reg
        int gn = n0 + wn * 64 + j * 16 + mrow;             //      col=lane&15
        float v = acc[i][j][r];
        if constexpr (MODE == 0) {
          PO[(long)z * M * N + (long)gm * N + gn] = v;
        } else if constexpr (MODE == 1) {
          int b_ = gm >> 9, tok = gm & 511;
          int seg = gn / 768, nn = gn - seg * 768;
          int head = nn >> 6, e = nn & 63;
          long bh = (long)(b_ * 12 + head);
          if (seg == 0)      O1[(bh * 512 + tok) * 64 + e] = (bf16)(v + b0[nn]);
          else if (seg == 1) O2[(bh * 512 + tok) * 64 + e] = (bf16)(v + b1[nn]);
          else               O3[(bh * 64 + e) * 512 + tok] = (bf16)(v + b2[nn]);
        } else if constexpr (MODE == 2) {
          O1[(long)z * 262144 + (long)gm * 512 + gn] = (bf16)(v * 0.125f);
        } else if constexpr (MODE == 3) {
          PO[(long)s3 * 1572864 + ((long)(b3 * 512 + gm)) * 768 + h3 * 64 + gn] = v;
        } else {
          O1[(long)gm * N + gn] = (bf16)gelu_f(v + b0[gn]);
        }
      }
    }
  }
}

// ---------------------------------------------------------------- launch ----
extern "C" void kernel_launch(void* const* d_in, const int* in_sizes, int n_in,
                              void* d_out, int out_size, void* d_ws, size_t ws_size,
                              hipStream_t stream) {
  const float* x     = (const float*)d_in[0];
  const float* Wp    = (const float*)d_in[1];
  const float* bp    = (const float*)d_in[2];
  const float* pos   = (const float*)d_in[3];
  const float* ln1_g = (const float*)d_in[4];
  const float* ln1_b = (const float*)d_in[5];
  const float* Wq    = (const float*)d_in[6];
  const float* bq    = (const float*)d_in[7];
  const float* Wk    = (const float*)d_in[8];
  const float* bk    = (const float*)d_in[9];
  const float* Wv    = (const float*)d_in[10];
  const float* bv    = (const float*)d_in[11];
  const float* ln2_g = (const float*)d_in[12];
  const float* ln2_b = (const float*)d_in[13];
  const float* W1    = (const float*)d_in[14];
  const float* b1    = (const float*)d_in[15];
  const float* W2    = (const float*)d_in[16];
  const float* b2    = (const float*)d_in[17];
  float* h = (float*)d_out;   // (4,512,768) residual stream lives in d_out

  // ---- workspace layout (bytes). Patch-phase buffers alias layer-phase ones:
  //   patches [0, 64M) + Ppatch [64M, 112M)  die before the layer loop's
  //   Y/Qb/Kb/Vt/Pb/Ub/Sb/Ppv/Pmlp2 overlay [0, 120M) is first written.
  char* wsp = (char*)d_ws;
  bf16*  patches = (bf16*)(wsp + 0);                   // 67,108,864
  float* Ppatch  = (float*)(wsp + 67108864);           // 8 * 6,291,456
  bf16*  Y       = (bf16*)(wsp + 0);                   // 3,145,728
  bf16*  Qb      = (bf16*)(wsp + 3145728);
  bf16*  Kb      = (bf16*)(wsp + 6291456);
  bf16*  Vt      = (bf16*)(wsp + 9437184);
  bf16*  Pb      = (bf16*)(wsp + 12582912);            // 25,165,824
  bf16*  Ub      = (bf16*)(wsp + 37748736);            // 12,582,912
  bf16*  Sb      = (bf16*)(wsp + 50331648);            // 25,165,824
  float* Ppv     = (float*)(wsp + 75497472);           // 25,165,824
  float* Pmlp2   = (float*)(wsp + 100663296);          // 25,165,824
  bf16*  Wp_bt   = (bf16*)(wsp + 125829120);           // 25,165,824
  bf16*  Wqkv    = (bf16*)(wsp + 150994944);           // 42,467,328
  bf16*  W1t     = (bf16*)(wsp + 193462272);           // 56,623,104
  bf16*  W2t     = (bf16*)(wsp + 250085376);           // 56,623,104

  // weight/activation prep
  im2col_k<<<dim3(16, 2048), 256, 0, stream>>>(x, patches);
  cvt_k<<<dim3(12288), 256, 0, stream>>>(Wp, Wp_bt);
  tp_qkv<<<dim3(12, 144), dim3(64, 4), 0, stream>>>(Wq, Wqkv, 0);
  tp_qkv<<<dim3(12, 144), dim3(64, 4), 0, stream>>>(Wk, Wqkv, 768);
  tp_qkv<<<dim3(12, 144), dim3(64, 4), 0, stream>>>(Wv, Wqkv, 1536);
  tp_gen<<<dim3(12, 48, 12), dim3(64, 4), 0, stream>>>(W1, W1t, 768, 3072);
  tp_gen<<<dim3(48, 12, 12), dim3(64, 4), 0, stream>>>(W2, W2t, 3072, 768);

  // patch embed, split-K x8: Ppatch[s] = patches @ Wp^T (K chunk 2048)
  gemm_bt<128, 128, 0><<<dim3(16, 6, 8), 256, 0, stream>>>(
      patches, Wp_bt, 2048, 768, 16384, 2048, 2048, 0, 0,
      nullptr, nullptr, nullptr, Ppatch, nullptr, nullptr, nullptr);

  for (int l = 0; l < 12; l++) {
    // ln1 (+ split-K reduce of previous stage)
    if (l == 0)
      lnred_k<<<2048, 256, 0, stream>>>(nullptr, Ppatch, 8, bp, pos,
                                        ln1_g, ln1_b, h, Y);
    else
      lnred_k<<<2048, 256, 0, stream>>>(h, Pmlp2, 4, b2 + (l - 1) * 768, nullptr,
                                        ln1_g + l * 768, ln1_b + l * 768, h, Y);
    // QKV
    gemm_bt<64, 128, 1><<<dim3(32, 18), 128, 0, stream>>>(
        Y, Wqkv + (size_t)l * 2304 * 768, 2048, 2304, 768, 0, 768, 0, 0,
        bq + l * 768, bk + l * 768, bv + l * 768,
        nullptr, Qb, Kb, Vt);
    // scores -> bf16 S
    gemm_bt<128, 128, 2><<<dim3(4, 4, 48), 256, 0, stream>>>(
        Qb, Kb, 512, 512, 64, 0, 64, 512 * 64, 512 * 64,
        nullptr, nullptr, nullptr, nullptr, Sb, nullptr, nullptr);
    softmax_k<<<dim3(6144), 256, 0, stream>>>(Sb, Pb);
    // PV, split-K x4 -> Ppv
    gemm_bt<128, 64, 3><<<dim3(4, 1, 192), 128, 0, stream>>>(
        Pb, Vt, 512, 64, 512, 128, 128, 512 * 512, 64 * 512,
        nullptr, nullptr, nullptr, Ppv, nullptr, nullptr, nullptr);
    // ln2 (+ reduce of Ppv into h)
    lnred_k<<<2048, 256, 0, stream>>>(h, Ppv, 4, nullptr, nullptr,
                                      ln2_g + l * 768, ln2_b + l * 768, h, Y);
    // MLP1: gelu(Y @ W1 + b1) -> Ub
    gemm_bt<64, 128, 4><<<dim3(32, 24), 128, 0, stream>>>(
        Y, W1t + (size_t)l * 3072 * 768, 2048, 3072, 768, 0, 768, 0, 0,
        b1 + l * 3072, nullptr, nullptr, nullptr, Ub, nullptr, nullptr);
    // MLP2, split-K x4 -> Pmlp2 (reduced by next layer's ln1 / final reduce)
    gemm_bt<64, 128, 0><<<dim3(32, 6, 4), 128, 0, stream>>>(
        Ub, W2t + (size_t)l * 3072 * 768, 2048, 768, 3072, 768, 768, 0, 0,
        nullptr, nullptr, nullptr, Pmlp2, nullptr, nullptr, nullptr);
  }
  // final: h += sum(Pmlp2) + b2[11]  (no LN)
  lnred_k<<<2048, 256, 0, stream>>>(h, Pmlp2, 4, b2 + 11 * 768, nullptr,
                                    nullptr, nullptr, h, nullptr);
}